// Round 3
// baseline (1306.724 us; speedup 1.0000x reference)
//
#include <hip/hip_runtime.h>
#include <cstdint>
#include <cstddef>

#define B_ 8
#define T_ 4096
#define E_ 512
#define H_ 8
#define D_ 64

static __device__ __forceinline__ float bf2f(uint16_t h) {
    return __uint_as_float(((uint32_t)h) << 16);
}
static __device__ __forceinline__ uint16_t f2bf(float f) {
    uint32_t u = __float_as_uint(f);
    uint32_t r = (u + 0x7fffu + ((u >> 16) & 1u)) >> 16;   // round-to-nearest-even
    return (uint16_t)r;
}

// ---------------------------------------------------------------------------
// K1: dual GEMM  query = X@Wq+bq ; key = X@Wk+bk   (X = q input, f32)
// 128x128 tile, BK=16, 256 threads, 8x8 microtile. Output bf16 (intermediate).
// grid: (1024/128=8, 4096/128=32, B)
// ---------------------------------------------------------------------------
__global__ __launch_bounds__(256) void k_gemm_dual(
    const float* __restrict__ X,
    const float* __restrict__ Wq, const float* __restrict__ bq,
    const float* __restrict__ Wk, const float* __restrict__ bk,
    uint16_t* __restrict__ Qo, uint16_t* __restrict__ Ko)
{
    __shared__ float AsT[16][132];
    __shared__ float Bs[16][132];
    const int b  = blockIdx.z;
    const int m0 = blockIdx.y * 128;
    const int n0g = blockIdx.x * 128;            // 0..1023
    const bool isK = (n0g >= 512);
    const float* W    = isK ? Wk : Wq;
    const float* bias = isK ? bk : bq;
    const int n0 = isK ? (n0g - 512) : n0g;
    uint16_t* Out = isK ? Ko : Qo;
    const int tid = threadIdx.x;
    const int tx = tid & 15, ty = tid >> 4;
    const float* Xb = X + (size_t)b * T_ * E_;

    float acc[8][8];
#pragma unroll
    for (int i = 0; i < 8; i++)
#pragma unroll
        for (int j = 0; j < 8; j++) acc[i][j] = 0.f;

    for (int k0 = 0; k0 < E_; k0 += 16) {
#pragma unroll
        for (int q = 0; q < 2; q++) {            // A tile: 128x16
            int flat = q * 256 + tid;
            int row = flat >> 2, c4 = flat & 3;
            const float4 f = *reinterpret_cast<const float4*>(
                Xb + (size_t)(m0 + row) * E_ + k0 + c4 * 4);
            AsT[c4 * 4 + 0][row] = f.x;
            AsT[c4 * 4 + 1][row] = f.y;
            AsT[c4 * 4 + 2][row] = f.z;
            AsT[c4 * 4 + 3][row] = f.w;
        }
#pragma unroll
        for (int q = 0; q < 2; q++) {            // B tile: 16x128
            int flat = q * 256 + tid;
            int r = flat >> 5, c4 = flat & 31;
            const float4 f = *reinterpret_cast<const float4*>(
                W + (size_t)(k0 + r) * E_ + n0 + c4 * 4);
            *reinterpret_cast<float4*>(&Bs[r][c4 * 4]) = f;
        }
        __syncthreads();
#pragma unroll
        for (int kk = 0; kk < 16; kk++) {
            float a[8], bb[8];
            *reinterpret_cast<float4*>(a)     = *reinterpret_cast<const float4*>(&AsT[kk][ty * 8]);
            *reinterpret_cast<float4*>(a + 4) = *reinterpret_cast<const float4*>(&AsT[kk][ty * 8 + 4]);
            *reinterpret_cast<float4*>(bb)     = *reinterpret_cast<const float4*>(&Bs[kk][tx * 8]);
            *reinterpret_cast<float4*>(bb + 4) = *reinterpret_cast<const float4*>(&Bs[kk][tx * 8 + 4]);
#pragma unroll
            for (int i = 0; i < 8; i++)
#pragma unroll
                for (int j = 0; j < 8; j++)
                    acc[i][j] = fmaf(a[i], bb[j], acc[i][j]);
        }
        __syncthreads();
    }

    float bv[8];
#pragma unroll
    for (int j = 0; j < 8; j++) bv[j] = bias[n0 + tx * 8 + j];
#pragma unroll
    for (int i = 0; i < 8; i++) {
        int row = m0 + ty * 8 + i;
        uint16_t t[8];
#pragma unroll
        for (int j = 0; j < 8; j++) t[j] = f2bf(acc[i][j] + bv[j]);
        uint4 o;
        o.x = (uint32_t)t[0] | ((uint32_t)t[1] << 16);
        o.y = (uint32_t)t[2] | ((uint32_t)t[3] << 16);
        o.z = (uint32_t)t[4] | ((uint32_t)t[5] << 16);
        o.w = (uint32_t)t[6] | ((uint32_t)t[7] << 16);
        *reinterpret_cast<uint4*>(Out + (size_t)(b * T_ + row) * E_ + n0 + tx * 8) = o;
    }
}

// ---------------------------------------------------------------------------
// K2: scores = (Src ⊙ scaleIn?) @ Wsc + bsc    Src bf16 (B,T,E) -> (B,T,H) f32
// one wave per row; lane l owns e-range [l*8, l*8+8); W column slice in regs.
// grid: 512 blocks x 256 (2048 waves, 16 rows each)
// ---------------------------------------------------------------------------
__global__ __launch_bounds__(256) void k_scores(
    const uint16_t* __restrict__ Src,
    const float* __restrict__ scaleIn,     // (B,E) or nullptr
    const float* __restrict__ Wsc,         // (E,H) row-major
    const float* __restrict__ bsc,         // (H)
    float* __restrict__ Sc)                // (B,T,H)
{
    const int tid = threadIdx.x;
    const int lane = tid & 63;
    const int w = tid >> 6;
    float wv[64];
#pragma unroll
    for (int i = 0; i < 16; i++) {
        float4 f = *reinterpret_cast<const float4*>(Wsc + lane * 64 + i * 4);
        wv[i * 4 + 0] = f.x; wv[i * 4 + 1] = f.y;
        wv[i * 4 + 2] = f.z; wv[i * 4 + 3] = f.w;
    }
    float bias = (lane < H_) ? bsc[lane] : 0.f;
    const int waveGlobal = blockIdx.x * 4 + w;          // 0..2047

    for (int it = 0; it < 16; ++it) {
        int rowg = it * 2048 + waveGlobal;              // 0..32767
        int b = rowg >> 12;
        uint4 r = *reinterpret_cast<const uint4*>(Src + (size_t)rowg * E_ + lane * 8);
        float x[8];
        x[0] = bf2f((uint16_t)(r.x & 0xffff)); x[1] = bf2f((uint16_t)(r.x >> 16));
        x[2] = bf2f((uint16_t)(r.y & 0xffff)); x[3] = bf2f((uint16_t)(r.y >> 16));
        x[4] = bf2f((uint16_t)(r.z & 0xffff)); x[5] = bf2f((uint16_t)(r.z >> 16));
        x[6] = bf2f((uint16_t)(r.w & 0xffff)); x[7] = bf2f((uint16_t)(r.w >> 16));
        if (scaleIn) {
#pragma unroll
            for (int j = 0; j < 8; j++) x[j] *= scaleIn[b * E_ + lane * 8 + j];
        }
        float acc[8];
#pragma unroll
        for (int h = 0; h < 8; h++) acc[h] = 0.f;
#pragma unroll
        for (int j = 0; j < 8; j++)
#pragma unroll
            for (int h = 0; h < 8; h++)
                acc[h] = fmaf(x[j], wv[j * 8 + h], acc[h]);
#pragma unroll
        for (int m = 32; m >= 1; m >>= 1)
#pragma unroll
            for (int h = 0; h < 8; h++)
                acc[h] += __shfl_xor(acc[h], m, 64);
        if (lane < 8) {
            float v = acc[0];
#pragma unroll
            for (int h = 1; h < 8; h++) if (lane == h) v = acc[h];
            Sc[(size_t)rowg * H_ + lane] = v + bias;
        }
    }
}

// ---------------------------------------------------------------------------
// K3: masked softmax over T + weighted pool.
// Outv[b, h*64+d] = (scaleOut?) * sum_t softmax(Sc[b,:,h]/8, mask)[t] * Src[b,t,h*64+d]
// one block per (b,h); grid 64 x 256 threads
// ---------------------------------------------------------------------------
__global__ __launch_bounds__(256) void k_softpool(
    const float* __restrict__ Sc,        // (B,T,H)
    const int* __restrict__ mask,        // (B,T), nonzero = padded
    const uint16_t* __restrict__ Src,    // (B,T,E) bf16
    const float* __restrict__ scaleOut,  // (B,E) or nullptr
    float* __restrict__ Outv)            // (B,E)
{
    __shared__ float sw[T_];
    __shared__ float red[256];
    __shared__ float part[4][64];
    const int b = blockIdx.x >> 3, h = blockIdx.x & 7;
    const int tid = threadIdx.x;

    float lmax = -1e30f;
    for (int t = tid; t < T_; t += 256) {
        float s = Sc[((size_t)b * T_ + t) * H_ + h] * 0.125f;   // /sqrt(64)
        if (mask[b * T_ + t]) s = -1e30f;                       // finite sentinel
        sw[t] = s;
        lmax = fmaxf(lmax, s);
    }
    red[tid] = lmax; __syncthreads();
    for (int s = 128; s > 0; s >>= 1) {
        if (tid < s) red[tid] = fmaxf(red[tid], red[tid + s]);
        __syncthreads();
    }
    float M = red[0];
    __syncthreads();

    float lsum = 0.f;
    for (int t = tid; t < T_; t += 256) {
        float e = __expf(sw[t] - M);     // masked rows underflow to exactly 0
        sw[t] = e;
        lsum += e;
    }
    red[tid] = lsum; __syncthreads();
    for (int s = 128; s > 0; s >>= 1) {
        if (tid < s) red[tid] += red[tid + s];
        __syncthreads();
    }
    float inv = 1.f / red[0];

    const int g = tid >> 6, d = tid & 63;
    float acc = 0.f;
    for (int t = g; t < T_; t += 4)
        acc += sw[t] * bf2f(Src[((size_t)(b * T_ + t)) * E_ + h * D_ + d]);
    part[g][d] = acc;
    __syncthreads();
    if (tid < 64) {
        float tot = (part[0][tid] + part[1][tid] + part[2][tid] + part[3][tid]) * inv;
        int e = h * D_ + tid;
        if (scaleOut) tot *= scaleOut[b * E_ + e];
        Outv[b * E_ + e] = tot;
    }
}

// ---------------------------------------------------------------------------
// K6: out = (query ⊙ ksum_flat) @ Wo + bo + query     -> f32 d_out
// same tiling as K1; per-k scale folded into the A-tile load.
// grid: (512/128=4, 32, B)
// ---------------------------------------------------------------------------
__global__ __launch_bounds__(256) void k_gemm_out(
    const uint16_t* __restrict__ Q,     // query bf16 (B,T,E)
    const float* __restrict__ ksum,     // (B,E)
    const float* __restrict__ Wo, const float* __restrict__ bo,
    float* __restrict__ Outp)           // (B,T,E) f32
{
    __shared__ float AsT[16][132];
    __shared__ float Bs[16][132];
    const int b  = blockIdx.z;
    const int m0 = blockIdx.y * 128;
    const int n0 = blockIdx.x * 128;
    const int tid = threadIdx.x;
    const int tx = tid & 15, ty = tid >> 4;
    const uint16_t* Qb = Q + (size_t)b * T_ * E_;
    const float* sb = ksum + b * E_;

    float acc[8][8];
#pragma unroll
    for (int i = 0; i < 8; i++)
#pragma unroll
        for (int j = 0; j < 8; j++) acc[i][j] = 0.f;

    for (int k0 = 0; k0 < E_; k0 += 16) {
#pragma unroll
        for (int q = 0; q < 2; q++) {            // A tile 128x16 (bf16 -> f32, scaled)
            int flat = q * 256 + tid;
            int row = flat >> 2, c4 = flat & 3;
            ushort4 r4 = *reinterpret_cast<const ushort4*>(
                Qb + (size_t)(m0 + row) * E_ + k0 + c4 * 4);
            AsT[c4 * 4 + 0][row] = bf2f(r4.x) * sb[k0 + c4 * 4 + 0];
            AsT[c4 * 4 + 1][row] = bf2f(r4.y) * sb[k0 + c4 * 4 + 1];
            AsT[c4 * 4 + 2][row] = bf2f(r4.z) * sb[k0 + c4 * 4 + 2];
            AsT[c4 * 4 + 3][row] = bf2f(r4.w) * sb[k0 + c4 * 4 + 3];
        }
#pragma unroll
        for (int q = 0; q < 2; q++) {            // B tile 16x128
            int flat = q * 256 + tid;
            int r = flat >> 5, c4 = flat & 31;
            const float4 f = *reinterpret_cast<const float4*>(
                Wo + (size_t)(k0 + r) * E_ + n0 + c4 * 4);
            *reinterpret_cast<float4*>(&Bs[r][c4 * 4]) = f;
        }
        __syncthreads();
#pragma unroll
        for (int kk = 0; kk < 16; kk++) {
            float a[8], bb[8];
            *reinterpret_cast<float4*>(a)     = *reinterpret_cast<const float4*>(&AsT[kk][ty * 8]);
            *reinterpret_cast<float4*>(a + 4) = *reinterpret_cast<const float4*>(&AsT[kk][ty * 8 + 4]);
            *reinterpret_cast<float4*>(bb)     = *reinterpret_cast<const float4*>(&Bs[kk][tx * 8]);
            *reinterpret_cast<float4*>(bb + 4) = *reinterpret_cast<const float4*>(&Bs[kk][tx * 8 + 4]);
#pragma unroll
            for (int i = 0; i < 8; i++)
#pragma unroll
                for (int j = 0; j < 8; j++)
                    acc[i][j] = fmaf(a[i], bb[j], acc[i][j]);
        }
        __syncthreads();
    }

    float bv[8];
#pragma unroll
    for (int j = 0; j < 8; j++) bv[j] = bo[n0 + tx * 8 + j];
#pragma unroll
    for (int i = 0; i < 8; i++) {
        size_t rb = (size_t)(b * T_ + m0 + ty * 8 + i) * E_ + n0 + tx * 8;
        ushort4 q0 = *reinterpret_cast<const ushort4*>(Qb + ((size_t)(m0 + ty * 8 + i)) * E_ + n0 + tx * 8);
        ushort4 q1 = *reinterpret_cast<const ushort4*>(Qb + ((size_t)(m0 + ty * 8 + i)) * E_ + n0 + tx * 8 + 4);
        float qv[8] = { bf2f(q0.x), bf2f(q0.y), bf2f(q0.z), bf2f(q0.w),
                        bf2f(q1.x), bf2f(q1.y), bf2f(q1.z), bf2f(q1.w) };
        float o0[4], o1[4];
#pragma unroll
        for (int j = 0; j < 4; j++) o0[j] = acc[i][j] + bv[j] + qv[j];
#pragma unroll
        for (int j = 0; j < 4; j++) o1[j] = acc[i][j + 4] + bv[j + 4] + qv[j + 4];
        *reinterpret_cast<float4*>(Outp + rb)     = *reinterpret_cast<float4*>(o0);
        *reinterpret_cast<float4*>(Outp + rb + 4) = *reinterpret_cast<float4*>(o1);
    }
}

// ---------------------------------------------------------------------------
extern "C" void kernel_launch(void* const* d_in, const int* in_sizes, int n_in,
                              void* d_out, int out_size, void* d_ws, size_t ws_size,
                              hipStream_t stream)
{
    const float* q   = (const float*)d_in[0];
    // d_in[1] = k, d_in[2] = v : ignored by the module
    const int*   mask = (const int*)d_in[3];
    const float* Wq  = (const float*)d_in[4];
    const float* bq  = (const float*)d_in[5];
    const float* Waq = (const float*)d_in[6];
    const float* baq = (const float*)d_in[7];
    const float* Wk  = (const float*)d_in[8];
    const float* bk  = (const float*)d_in[9];
    const float* Wak = (const float*)d_in[10];
    const float* bak = (const float*)d_in[11];
    const float* Wo  = (const float*)d_in[12];
    const float* bo  = (const float*)d_in[13];
    float* out = (float*)d_out;    // reference output dtype is float32

    char* ws = (char*)d_ws;
    uint16_t* query = (uint16_t*)(ws);                    // 33.55 MB
    uint16_t* key   = (uint16_t*)(ws + 33554432);         // 33.55 MB
    float*    sc    = (float*)(ws + 67108864);            // 1 MB (reused q/k scores)
    float*    qflat = (float*)(ws + 68157440);            // 16 KB
    float*    ksum  = (float*)(ws + 68173824);            // 16 KB

    k_gemm_dual<<<dim3(8, 32, 8), 256, 0, stream>>>(q, Wq, bq, Wk, bk, query, key);
    k_scores<<<512, 256, 0, stream>>>(query, nullptr, Waq, baq, sc);
    k_softpool<<<64, 256, 0, stream>>>(sc, mask, query, nullptr, qflat);
    k_scores<<<512, 256, 0, stream>>>(key, qflat, Wak, bak, sc);
    k_softpool<<<64, 256, 0, stream>>>(sc, mask, key, qflat, ksum);
    k_gemm_out<<<dim3(4, 32, 8), 256, 0, stream>>>(query, ksum, Wo, bo, out);
}

// Round 4
// 531.086 us; speedup vs baseline: 2.4605x; 2.4605x over previous
//
#include <hip/hip_runtime.h>
#include <cstdint>
#include <cstddef>

#define B_ 8
#define T_ 4096
#define E_ 512
#define H_ 8
#define D_ 64

typedef short bf16x8 __attribute__((ext_vector_type(8)));
typedef float f32x4  __attribute__((ext_vector_type(4)));

static __device__ __forceinline__ float bf2f(uint16_t h) {
    return __uint_as_float(((uint32_t)h) << 16);
}
static __device__ __forceinline__ uint16_t f2bf(float f) {
    uint32_t u = __float_as_uint(f);
    uint32_t r = (u + 0x7fffu + ((u >> 16) & 1u)) >> 16;   // RNE
    return (uint16_t)r;
}
static __device__ __forceinline__ uint32_t pk2(float a, float b) {
    return (uint32_t)f2bf(a) | ((uint32_t)f2bf(b) << 16);
}

// ---------------------------------------------------------------------------
// cast/transpose weights: Wt[n][k] bf16 = W[k][n]   (512x512 each, 3 mats)
// grid (512, 3) x 256
// ---------------------------------------------------------------------------
__global__ __launch_bounds__(256) void k_cast_wT(
    const float* __restrict__ Wq, const float* __restrict__ Wk,
    const float* __restrict__ Wo,
    uint16_t* __restrict__ WtQ, uint16_t* __restrict__ WtK,
    uint16_t* __restrict__ WtO)
{
    const int n = blockIdx.x, mat = blockIdx.y;
    const float* In = (mat == 0) ? Wq : (mat == 1) ? Wk : Wo;
    uint16_t* Ot = (mat == 0) ? WtQ : (mat == 1) ? WtK : WtO;
    for (int k = threadIdx.x; k < E_; k += 256)
        Ot[n * E_ + k] = f2bf(In[(size_t)k * E_ + n]);
}

// ---------------------------------------------------------------------------
// GEMM1 (MFMA): query|key = X @ {Wq|Wk} + bias, bf16 out.
// 128x128 tile, BK=32, 4 waves (2x2), 4x4 16x16x32 frags per wave.
// grid 2048 = 256 mblk x 8 nblk (nblk>=4 -> K path). XCD swizzle.
// ---------------------------------------------------------------------------
__global__ __launch_bounds__(256) void k_gemm1(
    const float* __restrict__ X,        // (32768, 512) f32
    const uint16_t* __restrict__ WtQ,   // (512 n, 512 k) bf16
    const uint16_t* __restrict__ WtK,
    const float* __restrict__ bq, const float* __restrict__ bk,
    uint16_t* __restrict__ Qo, uint16_t* __restrict__ Ko)
{
    __shared__ uint16_t As[128 * 32];
    __shared__ uint16_t Bs[128 * 32];
    const int bid = blockIdx.x;
    const int logical = (bid & 7) * 256 + (bid >> 3);   // XCD-aware swizzle (nwg=2048)
    const int mblk = logical >> 3, nblk = logical & 7;
    const bool isK = (nblk >= 4);
    const uint16_t* Wt = isK ? WtK : WtQ;
    const float* bias  = isK ? bk : bq;
    uint16_t* Out      = isK ? Ko : Qo;
    const int n0 = (nblk & 3) * 128;
    const int m0 = mblk * 128;
    const int tid = threadIdx.x;
    const int lane = tid & 63, w = tid >> 6;
    const int wm = w >> 1, wn = w & 1;
    const int row16 = lane >> 2, ch = lane & 3;       // staging: row-in-16, 8-elem chunk
    const int fr = lane & 15, fk = (lane >> 4) * 8;   // fragment row / k-offset

    f32x4 acc[4][4];
#pragma unroll
    for (int i = 0; i < 4; i++)
#pragma unroll
        for (int j = 0; j < 4; j++) { acc[i][j][0]=0.f; acc[i][j][1]=0.f; acc[i][j][2]=0.f; acc[i][j][3]=0.f; }

    for (int k0 = 0; k0 < E_; k0 += 32) {
        uint4 av[2], bv[2];
#pragma unroll
        for (int cc = 0; cc < 2; ++cc) {
            const int c = w * 2 + cc;
            const float* ga = X + (size_t)(m0 + 16 * c + row16) * E_ + k0 + ch * 8;
            const float4 f0 = *reinterpret_cast<const float4*>(ga);
            const float4 f1 = *reinterpret_cast<const float4*>(ga + 4);
            av[cc].x = pk2(f0.x, f0.y); av[cc].y = pk2(f0.z, f0.w);
            av[cc].z = pk2(f1.x, f1.y); av[cc].w = pk2(f1.z, f1.w);
            bv[cc] = *reinterpret_cast<const uint4*>(
                Wt + (size_t)(n0 + 16 * c + row16) * E_ + k0 + ch * 8);
        }
        __syncthreads();
#pragma unroll
        for (int cc = 0; cc < 2; ++cc) {
            const int c = w * 2 + cc;
            *reinterpret_cast<uint4*>(&As[c * 512 + lane * 8]) = av[cc];
            *reinterpret_cast<uint4*>(&Bs[c * 512 + lane * 8]) = bv[cc];
        }
        __syncthreads();
        bf16x8 af[4], bfr[4];
#pragma unroll
        for (int mf = 0; mf < 4; ++mf)
            af[mf] = *reinterpret_cast<const bf16x8*>(&As[(wm * 64 + mf * 16 + fr) * 32 + fk]);
#pragma unroll
        for (int nf = 0; nf < 4; ++nf)
            bfr[nf] = *reinterpret_cast<const bf16x8*>(&Bs[(wn * 64 + nf * 16 + fr) * 32 + fk]);
#pragma unroll
        for (int mf = 0; mf < 4; ++mf)
#pragma unroll
            for (int nf = 0; nf < 4; ++nf)
                acc[mf][nf] = __builtin_amdgcn_mfma_f32_16x16x32_bf16(
                    af[mf], bfr[nf], acc[mf][nf], 0, 0, 0);
    }

    const int orow = (lane >> 4) * 4;
#pragma unroll
    for (int nf = 0; nf < 4; ++nf) {
        const int gc = n0 + wn * 64 + nf * 16 + fr;
        const float bvs = bias[gc];
#pragma unroll
        for (int mf = 0; mf < 4; ++mf) {
            const int gr = m0 + wm * 64 + mf * 16 + orow;
#pragma unroll
            for (int rr = 0; rr < 4; ++rr)
                Out[(size_t)(gr + rr) * E_ + gc] = f2bf(acc[mf][nf][rr] + bvs);
        }
    }
}

// ---------------------------------------------------------------------------
// GEMM2 (MFMA): out = query @ WtOs[b] + bo + query   -> f32 d_out
// WtOs already holds diag(qflat*kpool) @ Wo transposed, per batch.
// grid 1024 = 256 mblk x 4 nblk. XCD swizzle.
// ---------------------------------------------------------------------------
__global__ __launch_bounds__(256) void k_gemm2(
    const uint16_t* __restrict__ Q,      // query bf16 (32768, 512)
    const uint16_t* __restrict__ WtOs,   // (8, 512 n, 512 k) bf16
    const float* __restrict__ bo,
    float* __restrict__ Outp)            // (32768, 512) f32
{
    __shared__ uint16_t As[128 * 32];
    __shared__ uint16_t Bs[128 * 32];
    const int bid = blockIdx.x;
    const int logical = (bid & 7) * 128 + (bid >> 3);   // nwg=1024
    const int mblk = logical >> 2, nblk = logical & 3;
    const int m0 = mblk * 128, n0 = nblk * 128;
    const uint16_t* Wt = WtOs + (size_t)(m0 >> 12) * (E_ * E_);
    const int tid = threadIdx.x;
    const int lane = tid & 63, w = tid >> 6;
    const int wm = w >> 1, wn = w & 1;
    const int row16 = lane >> 2, ch = lane & 3;
    const int fr = lane & 15, fk = (lane >> 4) * 8;

    f32x4 acc[4][4];
#pragma unroll
    for (int i = 0; i < 4; i++)
#pragma unroll
        for (int j = 0; j < 4; j++) { acc[i][j][0]=0.f; acc[i][j][1]=0.f; acc[i][j][2]=0.f; acc[i][j][3]=0.f; }

    for (int k0 = 0; k0 < E_; k0 += 32) {
        uint4 av[2], bv[2];
#pragma unroll
        for (int cc = 0; cc < 2; ++cc) {
            const int c = w * 2 + cc;
            av[cc] = *reinterpret_cast<const uint4*>(
                Q + (size_t)(m0 + 16 * c + row16) * E_ + k0 + ch * 8);
            bv[cc] = *reinterpret_cast<const uint4*>(
                Wt + (size_t)(n0 + 16 * c + row16) * E_ + k0 + ch * 8);
        }
        __syncthreads();
#pragma unroll
        for (int cc = 0; cc < 2; ++cc) {
            const int c = w * 2 + cc;
            *reinterpret_cast<uint4*>(&As[c * 512 + lane * 8]) = av[cc];
            *reinterpret_cast<uint4*>(&Bs[c * 512 + lane * 8]) = bv[cc];
        }
        __syncthreads();
        bf16x8 af[4], bfr[4];
#pragma unroll
        for (int mf = 0; mf < 4; ++mf)
            af[mf] = *reinterpret_cast<const bf16x8*>(&As[(wm * 64 + mf * 16 + fr) * 32 + fk]);
#pragma unroll
        for (int nf = 0; nf < 4; ++nf)
            bfr[nf] = *reinterpret_cast<const bf16x8*>(&Bs[(wn * 64 + nf * 16 + fr) * 32 + fk]);
#pragma unroll
        for (int mf = 0; mf < 4; ++mf)
#pragma unroll
            for (int nf = 0; nf < 4; ++nf)
                acc[mf][nf] = __builtin_amdgcn_mfma_f32_16x16x32_bf16(
                    af[mf], bfr[nf], acc[mf][nf], 0, 0, 0);
    }

    const int orow = (lane >> 4) * 4;
#pragma unroll
    for (int nf = 0; nf < 4; ++nf) {
        const int gc = n0 + wn * 64 + nf * 16 + fr;
        const float bvs = bo[gc];
#pragma unroll
        for (int mf = 0; mf < 4; ++mf) {
            const int gr = m0 + wm * 64 + mf * 16 + orow;
#pragma unroll
            for (int rr = 0; rr < 4; ++rr) {
                const size_t idx = (size_t)(gr + rr) * E_ + gc;
                Outp[idx] = acc[mf][nf][rr] + bvs + bf2f(Q[idx]);
            }
        }
    }
}

// ---------------------------------------------------------------------------
// scores = (Src ⊙ scaleIn?) @ Wsc + bsc  -> scT (B,H,T) f32 (transposed!)
// grid 512 x 256
// ---------------------------------------------------------------------------
__global__ __launch_bounds__(256) void k_scores(
    const uint16_t* __restrict__ Src,
    const float* __restrict__ scaleIn,     // (B,E) or nullptr
    const float* __restrict__ Wsc,         // (E,H) row-major
    const float* __restrict__ bsc,         // (H)
    float* __restrict__ ScT)               // (B,H,T)
{
    const int tid = threadIdx.x;
    const int lane = tid & 63;
    const int w = tid >> 6;
    float wv[64];
#pragma unroll
    for (int i = 0; i < 16; i++) {
        float4 f = *reinterpret_cast<const float4*>(Wsc + lane * 64 + i * 4);
        wv[i * 4 + 0] = f.x; wv[i * 4 + 1] = f.y;
        wv[i * 4 + 2] = f.z; wv[i * 4 + 3] = f.w;
    }
    float bias = (lane < H_) ? bsc[lane] : 0.f;
    const int waveGlobal = blockIdx.x * 4 + w;          // 0..2047

    for (int it = 0; it < 16; ++it) {
        int rowg = it * 2048 + waveGlobal;              // 0..32767
        int b = rowg >> 12;
        uint4 r = *reinterpret_cast<const uint4*>(Src + (size_t)rowg * E_ + lane * 8);
        float x[8];
        x[0] = bf2f((uint16_t)(r.x & 0xffff)); x[1] = bf2f((uint16_t)(r.x >> 16));
        x[2] = bf2f((uint16_t)(r.y & 0xffff)); x[3] = bf2f((uint16_t)(r.y >> 16));
        x[4] = bf2f((uint16_t)(r.z & 0xffff)); x[5] = bf2f((uint16_t)(r.z >> 16));
        x[6] = bf2f((uint16_t)(r.w & 0xffff)); x[7] = bf2f((uint16_t)(r.w >> 16));
        if (scaleIn) {
#pragma unroll
            for (int j = 0; j < 8; j++) x[j] *= scaleIn[b * E_ + lane * 8 + j];
        }
        float acc[8];
#pragma unroll
        for (int h = 0; h < 8; h++) acc[h] = 0.f;
#pragma unroll
        for (int j = 0; j < 8; j++)
#pragma unroll
            for (int h = 0; h < 8; h++)
                acc[h] = fmaf(x[j], wv[j * 8 + h], acc[h]);
#pragma unroll
        for (int m = 32; m >= 1; m >>= 1)
#pragma unroll
            for (int h = 0; h < 8; h++)
                acc[h] += __shfl_xor(acc[h], m, 64);
        if (lane < 8) {
            float v = acc[0];
#pragma unroll
            for (int h = 1; h < 8; h++) if (lane == h) v = acc[h];
            ScT[((size_t)(b * H_ + lane)) * T_ + (rowg & (T_ - 1))] = v + bias;
        }
    }
}

// ---------------------------------------------------------------------------
// masked softmax over T, in place on scT[bh][t]. grid 64 x 256.
// ---------------------------------------------------------------------------
__global__ __launch_bounds__(256) void k_softmaxw(
    float* __restrict__ ScT, const int* __restrict__ mask)
{
    const int bh = blockIdx.x, b = bh >> 3;
    float* S = ScT + (size_t)bh * T_;
    const int* mk = mask + b * T_;
    __shared__ float red[256];
    const int tid = threadIdx.x;

    float sv[16];
    float lmax = -1e30f;
#pragma unroll
    for (int i = 0; i < 16; i++) {
        int t = i * 256 + tid;
        float s = S[t] * 0.125f;            // /sqrt(D)
        if (mk[t]) s = -1e30f;
        sv[i] = s;
        lmax = fmaxf(lmax, s);
    }
    red[tid] = lmax; __syncthreads();
    for (int s = 128; s > 0; s >>= 1) {
        if (tid < s) red[tid] = fmaxf(red[tid], red[tid + s]);
        __syncthreads();
    }
    const float M = red[0];
    __syncthreads();

    float lsum = 0.f;
#pragma unroll
    for (int i = 0; i < 16; i++) {
        float e = __expf(sv[i] - M);        // masked -> exactly 0
        sv[i] = e;
        lsum += e;
    }
    red[tid] = lsum; __syncthreads();
    for (int s = 128; s > 0; s >>= 1) {
        if (tid < s) red[tid] += red[tid + s];
        __syncthreads();
    }
    const float inv = 1.f / red[0];
#pragma unroll
    for (int i = 0; i < 16; i++)
        S[i * 256 + tid] = sv[i] * inv;
}

// ---------------------------------------------------------------------------
// weighted pool: Outv[b, h*64+d] += sum_{t in chunk} w[t] * Src[b,t,h*64+d]
// grid (64 bh, 8 chunks) x 256; Outv pre-zeroed; atomicAdd partials.
// ---------------------------------------------------------------------------
__global__ __launch_bounds__(256) void k_pool(
    const float* __restrict__ ScT,       // weights (B,H,T)
    const uint16_t* __restrict__ Src,    // (B,T,E) bf16
    float* __restrict__ Outv)            // (B,E), zero-initialized
{
    const int bh = blockIdx.x, chunk = blockIdx.y;
    const int b = bh >> 3, h = bh & 7;
    const int t0 = chunk * 512;
    const float* wv = ScT + (size_t)bh * T_ + t0;
    __shared__ float part[4][64];
    const int tid = threadIdx.x;
    const int g = tid >> 6, d = tid & 63;

    float acc = 0.f;
    for (int t = g; t < 512; t += 4)
        acc += wv[t] * bf2f(Src[(size_t)(b * T_ + t0 + t) * E_ + h * D_ + d]);
    part[g][d] = acc;
    __syncthreads();
    if (tid < 64)
        atomicAdd(&Outv[b * E_ + h * D_ + tid],
                  part[0][tid] + part[1][tid] + part[2][tid] + part[3][tid]);
}

// ---------------------------------------------------------------------------
// WtOs[b][n][k] = WtO[n][k] * kpool[b][k] * qflat[b][k]   (bf16)
// grid (512 n, 8 b) x 256
// ---------------------------------------------------------------------------
__global__ __launch_bounds__(256) void k_scale_wo(
    const uint16_t* __restrict__ WtO,
    const float* __restrict__ kpool, const float* __restrict__ qflat,
    uint16_t* __restrict__ WtOs)
{
    const int n = blockIdx.x, b = blockIdx.y;
    const float* s1 = kpool + b * E_;
    const float* s2 = qflat + b * E_;
    const int k = threadIdx.x * 2;
    ushort2 wv = *reinterpret_cast<const ushort2*>(&WtO[n * E_ + k]);
    ushort2 o;
    o.x = f2bf(bf2f(wv.x) * s1[k] * s2[k]);
    o.y = f2bf(bf2f(wv.y) * s1[k + 1] * s2[k + 1]);
    *reinterpret_cast<ushort2*>(&WtOs[((size_t)b * E_ + n) * E_ + k]) = o;
}

// ---------------------------------------------------------------------------
extern "C" void kernel_launch(void* const* d_in, const int* in_sizes, int n_in,
                              void* d_out, int out_size, void* d_ws, size_t ws_size,
                              hipStream_t stream)
{
    const float* q    = (const float*)d_in[0];
    const int*   mask = (const int*)d_in[3];
    const float* Wq   = (const float*)d_in[4];
    const float* bq   = (const float*)d_in[5];
    const float* Waq  = (const float*)d_in[6];
    const float* baq  = (const float*)d_in[7];
    const float* Wk   = (const float*)d_in[8];
    const float* bk   = (const float*)d_in[9];
    const float* Wak  = (const float*)d_in[10];
    const float* bak  = (const float*)d_in[11];
    const float* Wo   = (const float*)d_in[12];
    const float* bo   = (const float*)d_in[13];
    float* out = (float*)d_out;

    char* ws = (char*)d_ws;
    uint16_t* query = (uint16_t*)(ws);                    // 33.55 MB
    uint16_t* key   = (uint16_t*)(ws + 33554432);         // 33.55 MB
    float*    scT   = (float*)(ws + 67108864);            // 1 MB (B,H,T)
    float*    qflat = (float*)(ws + 68157440);            // 16 KB
    float*    kpool = (float*)(ws + 68173824);            // 16 KB
    uint16_t* WtQ   = (uint16_t*)(ws + 68190208);         // 512 KB
    uint16_t* WtK   = (uint16_t*)(ws + 68714496);         // 512 KB
    uint16_t* WtO   = (uint16_t*)(ws + 69238784);         // 512 KB
    uint16_t* WtOs  = (uint16_t*)(ws + 69763072);         // 4 MB

    hipMemsetAsync(qflat, 0, 32768, stream);              // qflat + kpool
    k_cast_wT<<<dim3(512, 3), 256, 0, stream>>>(Wq, Wk, Wo, WtQ, WtK, WtO);
    k_gemm1<<<2048, 256, 0, stream>>>(q, WtQ, WtK, bq, bk, query, key);
    k_scores<<<512, 256, 0, stream>>>(query, nullptr, Waq, baq, scT);
    k_softmaxw<<<64, 256, 0, stream>>>(scT, mask);
    k_pool<<<dim3(64, 8), 256, 0, stream>>>(scT, query, qflat);
    k_scores<<<512, 256, 0, stream>>>(key, qflat, Wak, bak, scT);
    k_softmaxw<<<64, 256, 0, stream>>>(scT, mask);
    k_pool<<<dim3(64, 8), 256, 0, stream>>>(scT, key, kpool);
    k_scale_wo<<<dim3(512, 8), 256, 0, stream>>>(WtO, kpool, qflat, WtOs);
    k_gemm2<<<1024, 256, 0, stream>>>(query, WtOs, bo, out);
}

// Round 8
// 412.798 us; speedup vs baseline: 3.1655x; 1.2866x over previous
//
#include <hip/hip_runtime.h>
#include <cstdint>
#include <cstddef>

#define B_ 8
#define T_ 4096
#define E_ 512
#define H_ 8
#define D_ 64

typedef short bf16x8 __attribute__((ext_vector_type(8)));
typedef float f32x4  __attribute__((ext_vector_type(4)));

static __device__ __forceinline__ float bf2f(uint16_t h) {
    return __uint_as_float(((uint32_t)h) << 16);
}
static __device__ __forceinline__ uint16_t f2bf(float f) {
    uint32_t u = __float_as_uint(f);
    uint32_t r = (u + 0x7fffu + ((u >> 16) & 1u)) >> 16;   // RNE
    return (uint16_t)r;
}
static __device__ __forceinline__ uint32_t pk2(float a, float b) {
    return (uint32_t)f2bf(a) | ((uint32_t)f2bf(b) << 16);
}
// async global->LDS, 16B per lane; lds base must be wave-uniform (HW adds lane*16)
static __device__ __forceinline__ void gld16(const void* g, void* l) {
    __builtin_amdgcn_global_load_lds(
        (const __attribute__((address_space(1))) uint32_t*)g,
        (__attribute__((address_space(3))) uint32_t*)l,
        16, 0, 0);
}

// ---------------------------------------------------------------------------
// prep: [blocks 0..8191]   Xb = bf16(X)  (32768x512)  — Xb lives in d_out scratch
//       [blocks 8192..8959] Wt{Q,K,O}[n][k] = bf16(W[k][n]) via LDS 32x32 tiles
// ---------------------------------------------------------------------------
__global__ __launch_bounds__(256) void k_prep(
    const float* __restrict__ X,
    const float* __restrict__ Wq, const float* __restrict__ Wk,
    const float* __restrict__ Wo,
    uint16_t* __restrict__ Xb,
    uint16_t* __restrict__ WtQ, uint16_t* __restrict__ WtK,
    uint16_t* __restrict__ WtO)
{
    __shared__ float L[32][33];
    const int bid = blockIdx.x, tid = threadIdx.x;
    if (bid < 8192) {                       // cast X
        const size_t base = ((size_t)bid * 256 + tid) * 8;
        const float4 f0 = *reinterpret_cast<const float4*>(X + base);
        const float4 f1 = *reinterpret_cast<const float4*>(X + base + 4);
        uint4 o;
        o.x = pk2(f0.x, f0.y); o.y = pk2(f0.z, f0.w);
        o.z = pk2(f1.x, f1.y); o.w = pk2(f1.z, f1.w);
        *reinterpret_cast<uint4*>(Xb + base) = o;
        return;
    }
    const int idx = bid - 8192;             // 0..767
    const int mat = idx >> 8, tile = idx & 255;
    const int k0 = (tile >> 4) * 32, n0 = (tile & 15) * 32;
    const float* In = (mat == 0) ? Wq : (mat == 1) ? Wk : Wo;
    uint16_t* Ot = (mat == 0) ? WtQ : (mat == 1) ? WtK : WtO;
    {
        const int r = tid >> 3, c4 = (tid & 7) * 4;
        const float4 f = *reinterpret_cast<const float4*>(In + (size_t)(k0 + r) * E_ + n0 + c4);
        L[r][c4] = f.x; L[r][c4 + 1] = f.y; L[r][c4 + 2] = f.z; L[r][c4 + 3] = f.w;
    }
    __syncthreads();
    {
        const int nl = tid >> 3, k4 = (tid & 7) * 4;
        ushort4 o;
        o.x = f2bf(L[k4 + 0][nl]); o.y = f2bf(L[k4 + 1][nl]);
        o.z = f2bf(L[k4 + 2][nl]); o.w = f2bf(L[k4 + 3][nl]);
        *reinterpret_cast<ushort4*>(Ot + (size_t)(n0 + nl) * E_ + k0 + k4) = o;
    }
}

// ---------------------------------------------------------------------------
// GEMM1 (MFMA): query|key = Xb @ {WtQ|WtK}^T + bias, bf16 out.
// 128x128 tile, BK=32, 4 waves (2x2), 4x4 16x16x32 frags, global_load_lds
// staging, LDS-transposed 16B-store epilogue. grid 2048, XCD swizzle.
// ---------------------------------------------------------------------------
__global__ __launch_bounds__(256) void k_gemm1(
    const uint16_t* __restrict__ Xb,    // (32768,512) bf16
    const uint16_t* __restrict__ WtQ,   // (512 n,512 k) bf16
    const uint16_t* __restrict__ WtK,
    const float* __restrict__ bq, const float* __restrict__ bk,
    uint16_t* __restrict__ Qo, uint16_t* __restrict__ Ko)
{
    __shared__ char smem[32768];
    uint16_t* As = (uint16_t*)smem;                 // [128][32] bf16, 8KB
    uint16_t* Bs = (uint16_t*)(smem + 8192);        // [128][32] bf16, 8KB
    const int bid = blockIdx.x;
    const int logical = (bid & 7) * 256 + (bid >> 3);   // XCD swizzle (nwg=2048)
    const int mblk = logical >> 3, nblk = logical & 7;
    const bool isK = (nblk >= 4);
    const uint16_t* Wt = isK ? WtK : WtQ;
    const float* bias  = isK ? bk : bq;
    uint16_t* Out      = isK ? Ko : Qo;
    const int n0 = (nblk & 3) * 128;
    const int m0 = mblk * 128;
    const int tid = threadIdx.x;
    const int lane = tid & 63, w = tid >> 6;
    const int wm = w >> 1, wn = w & 1;
    const int fr = lane & 15, fk = (lane >> 4) * 8;
    const int orow = (lane >> 4) * 4;

    f32x4 acc[4][4];
#pragma unroll
    for (int i = 0; i < 4; i++)
#pragma unroll
        for (int j = 0; j < 4; j++) { acc[i][j][0]=0.f; acc[i][j][1]=0.f; acc[i][j][2]=0.f; acc[i][j][3]=0.f; }

    for (int k0 = 0; k0 < E_; k0 += 32) {
#pragma unroll
        for (int i = 0; i < 2; ++i) {
            const int c = (w * 2 + i) * 64 + lane;       // 16B chunk idx in tile
            gld16(Xb + (size_t)(m0 + (c >> 2)) * E_ + k0 + (c & 3) * 8,
                  (char*)As + (w * 2 + i) * 1024);
        }
#pragma unroll
        for (int i = 0; i < 2; ++i) {
            const int c = (w * 2 + i) * 64 + lane;
            gld16(Wt + (size_t)(n0 + (c >> 2)) * E_ + k0 + (c & 3) * 8,
                  (char*)Bs + (w * 2 + i) * 1024);
        }
        __syncthreads();                                 // drains vmcnt
        bf16x8 af[4], bfr[4];
#pragma unroll
        for (int mf = 0; mf < 4; ++mf)
            af[mf] = *reinterpret_cast<const bf16x8*>(&As[(wm * 64 + mf * 16 + fr) * 32 + fk]);
#pragma unroll
        for (int nf = 0; nf < 4; ++nf)
            bfr[nf] = *reinterpret_cast<const bf16x8*>(&Bs[(wn * 64 + nf * 16 + fr) * 32 + fk]);
#pragma unroll
        for (int mf = 0; mf < 4; ++mf)
#pragma unroll
            for (int nf = 0; nf < 4; ++nf)
                acc[mf][nf] = __builtin_amdgcn_mfma_f32_16x16x32_bf16(
                    af[mf], bfr[nf], acc[mf][nf], 0, 0, 0);
        __syncthreads();
    }

    // epilogue: per-wave 64x64 bf16 region via own 8KB LDS slot, 16B stores
    float bvs[4];
#pragma unroll
    for (int nf = 0; nf < 4; ++nf) bvs[nf] = bias[n0 + wn * 64 + nf * 16 + fr];
    uint16_t* epi = (uint16_t*)(smem + w * 8192);        // [64][64] bf16
#pragma unroll
    for (int mf = 0; mf < 4; ++mf)
#pragma unroll
        for (int nf = 0; nf < 4; ++nf)
#pragma unroll
            for (int rr = 0; rr < 4; ++rr)
                epi[(mf * 16 + orow + rr) * 64 + nf * 16 + fr] =
                    f2bf(acc[mf][nf][rr] + bvs[nf]);
    // wave-local LDS dep; compiler inserts lgkmcnt
#pragma unroll
    for (int p = 0; p < 8; ++p) {
        const int o = p * 1024 + lane * 16;              // byte in 8KB region
        const int rl = o >> 7, colb = o & 127;
        const uint4 v = *reinterpret_cast<const uint4*>((char*)epi + o);
        *reinterpret_cast<uint4*>(
            Out + (size_t)(m0 + wm * 64 + rl) * E_ + n0 + wn * 64 + (colb >> 1)) = v;
    }
}

// ---------------------------------------------------------------------------
// GEMM2 (MFMA): out = query @ WtOs[b]^T + bo + query  -> f32 d_out
// same structure; f32 epilogue in two 32-row halves per wave. grid 1024.
// ---------------------------------------------------------------------------
__global__ __launch_bounds__(256) void k_gemm2(
    const uint16_t* __restrict__ Q,      // query bf16 (32768,512)
    const uint16_t* __restrict__ WtOs,   // (8,512 n,512 k) bf16
    const float* __restrict__ bo,
    float* __restrict__ Outp)            // (32768,512) f32
{
    __shared__ char smem[32768];
    uint16_t* As = (uint16_t*)smem;
    uint16_t* Bs = (uint16_t*)(smem + 8192);
    const int bid = blockIdx.x;
    const int logical = (bid & 7) * 128 + (bid >> 3);   // nwg=1024
    const int mblk = logical >> 2, nblk = logical & 3;
    const int m0 = mblk * 128, n0 = nblk * 128;
    const uint16_t* Wt = WtOs + (size_t)(m0 >> 12) * (E_ * E_);
    const int tid = threadIdx.x;
    const int lane = tid & 63, w = tid >> 6;
    const int wm = w >> 1, wn = w & 1;
    const int fr = lane & 15, fk = (lane >> 4) * 8;
    const int orow = (lane >> 4) * 4;

    f32x4 acc[4][4];
#pragma unroll
    for (int i = 0; i < 4; i++)
#pragma unroll
        for (int j = 0; j < 4; j++) { acc[i][j][0]=0.f; acc[i][j][1]=0.f; acc[i][j][2]=0.f; acc[i][j][3]=0.f; }

    for (int k0 = 0; k0 < E_; k0 += 32) {
#pragma unroll
        for (int i = 0; i < 2; ++i) {
            const int c = (w * 2 + i) * 64 + lane;
            gld16(Q + (size_t)(m0 + (c >> 2)) * E_ + k0 + (c & 3) * 8,
                  (char*)As + (w * 2 + i) * 1024);
        }
#pragma unroll
        for (int i = 0; i < 2; ++i) {
            const int c = (w * 2 + i) * 64 + lane;
            gld16(Wt + (size_t)(n0 + (c >> 2)) * E_ + k0 + (c & 3) * 8,
                  (char*)Bs + (w * 2 + i) * 1024);
        }
        __syncthreads();
        bf16x8 af[4], bfr[4];
#pragma unroll
        for (int mf = 0; mf < 4; ++mf)
            af[mf] = *reinterpret_cast<const bf16x8*>(&As[(wm * 64 + mf * 16 + fr) * 32 + fk]);
#pragma unroll
        for (int nf = 0; nf < 4; ++nf)
            bfr[nf] = *reinterpret_cast<const bf16x8*>(&Bs[(wn * 64 + nf * 16 + fr) * 32 + fk]);
#pragma unroll
        for (int mf = 0; mf < 4; ++mf)
#pragma unroll
            for (int nf = 0; nf < 4; ++nf)
                acc[mf][nf] = __builtin_amdgcn_mfma_f32_16x16x32_bf16(
                    af[mf], bfr[nf], acc[mf][nf], 0, 0, 0);
        __syncthreads();
    }

    // epilogue: per-wave 8KB f32 slot, two 32x64 halves; +bo +query; 16B stores
    float* epi = (float*)(smem + w * 8192);              // [32][64] f32
#pragma unroll
    for (int h = 0; h < 2; ++h) {
#pragma unroll
        for (int mfh = 0; mfh < 2; ++mfh)
#pragma unroll
            for (int nf = 0; nf < 4; ++nf)
#pragma unroll
                for (int rr = 0; rr < 4; ++rr)
                    epi[(mfh * 16 + orow + rr) * 64 + nf * 16 + fr] =
                        acc[h * 2 + mfh][nf][rr];
        // wave-local dep; then read back coalesced
#pragma unroll
        for (int p = 0; p < 8; ++p) {
            const int o = p * 1024 + lane * 16;          // byte in 8KB
            const int rl = o >> 8, colb = o & 255;
            const int col = colb >> 2;                   // f32 idx, mult of 4
            const int grow = m0 + wm * 64 + h * 32 + rl;
            const int gcol = n0 + wn * 64 + col;
            const float4 a = *reinterpret_cast<const float4*>((char*)epi + o);
            const float4 bv = *reinterpret_cast<const float4*>(bo + gcol);
            const ushort4 qv = *reinterpret_cast<const ushort4*>(Q + (size_t)grow * E_ + gcol);
            float4 ov;
            ov.x = a.x + bv.x + bf2f(qv.x);
            ov.y = a.y + bv.y + bf2f(qv.y);
            ov.z = a.z + bv.z + bf2f(qv.z);
            ov.w = a.w + bv.w + bf2f(qv.w);
            *reinterpret_cast<float4*>(Outp + (size_t)grow * E_ + gcol) = ov;
        }
        if (h == 0) __syncthreads();   // keep waves aligned before slot reuse
    }
}

// ---------------------------------------------------------------------------
// scores = (Src ⊙ scaleIn?) @ Wsc + bsc  -> scT (B,H,T) f32
// ---------------------------------------------------------------------------
__global__ __launch_bounds__(256) void k_scores(
    const uint16_t* __restrict__ Src,
    const float* __restrict__ scaleIn,     // (B,E) or nullptr
    const float* __restrict__ Wsc,         // (E,H) row-major
    const float* __restrict__ bsc,         // (H)
    float* __restrict__ ScT)               // (B,H,T)
{
    const int tid = threadIdx.x;
    const int lane = tid & 63;
    const int w = tid >> 6;
    float wv[64];
#pragma unroll
    for (int i = 0; i < 16; i++) {
        float4 f = *reinterpret_cast<const float4*>(Wsc + lane * 64 + i * 4);
        wv[i * 4 + 0] = f.x; wv[i * 4 + 1] = f.y;
        wv[i * 4 + 2] = f.z; wv[i * 4 + 3] = f.w;
    }
    float bias = (lane < H_) ? bsc[lane] : 0.f;
    const int waveGlobal = blockIdx.x * 4 + w;

    for (int it = 0; it < 16; ++it) {
        int rowg = it * 2048 + waveGlobal;
        int b = rowg >> 12;
        uint4 r = *reinterpret_cast<const uint4*>(Src + (size_t)rowg * E_ + lane * 8);
        float x[8];
        x[0] = bf2f((uint16_t)(r.x & 0xffff)); x[1] = bf2f((uint16_t)(r.x >> 16));
        x[2] = bf2f((uint16_t)(r.y & 0xffff)); x[3] = bf2f((uint16_t)(r.y >> 16));
        x[4] = bf2f((uint16_t)(r.z & 0xffff)); x[5] = bf2f((uint16_t)(r.z >> 16));
        x[6] = bf2f((uint16_t)(r.w & 0xffff)); x[7] = bf2f((uint16_t)(r.w >> 16));
        if (scaleIn) {
#pragma unroll
            for (int j = 0; j < 8; j++) x[j] *= scaleIn[b * E_ + lane * 8 + j];
        }
        float acc[8];
#pragma unroll
        for (int h = 0; h < 8; h++) acc[h] = 0.f;
#pragma unroll
        for (int j = 0; j < 8; j++)
#pragma unroll
            for (int h = 0; h < 8; h++)
                acc[h] = fmaf(x[j], wv[j * 8 + h], acc[h]);
#pragma unroll
        for (int m = 32; m >= 1; m >>= 1)
#pragma unroll
            for (int h = 0; h < 8; h++)
                acc[h] += __shfl_xor(acc[h], m, 64);
        if (lane < 8) {
            float v = acc[0];
#pragma unroll
            for (int h = 1; h < 8; h++) if (lane == h) v = acc[h];
            ScT[((size_t)(b * H_ + lane)) * T_ + (rowg & (T_ - 1))] = v + bias;
        }
    }
}

// ---------------------------------------------------------------------------
// masked softmax over T, in place on scT[bh][t]. grid 64 x 256.
// ---------------------------------------------------------------------------
__global__ __launch_bounds__(256) void k_softmaxw(
    float* __restrict__ ScT, const int* __restrict__ mask)
{
    const int bh = blockIdx.x, b = bh >> 3;
    float* S = ScT + (size_t)bh * T_;
    const int* mk = mask + b * T_;
    __shared__ float red[256];
    const int tid = threadIdx.x;

    float sv[16];
    float lmax = -1e30f;
#pragma unroll
    for (int i = 0; i < 16; i++) {
        int t = i * 256 + tid;
        float s = S[t] * 0.125f;
        if (mk[t]) s = -1e30f;
        sv[i] = s;
        lmax = fmaxf(lmax, s);
    }
    red[tid] = lmax; __syncthreads();
    for (int s = 128; s > 0; s >>= 1) {
        if (tid < s) red[tid] = fmaxf(red[tid], red[tid + s]);
        __syncthreads();
    }
    const float M = red[0];
    __syncthreads();

    float lsum = 0.f;
#pragma unroll
    for (int i = 0; i < 16; i++) {
        float e = __expf(sv[i] - M);
        sv[i] = e;
        lsum += e;
    }
    red[tid] = lsum; __syncthreads();
    for (int s = 128; s > 0; s >>= 1) {
        if (tid < s) red[tid] += red[tid + s];
        __syncthreads();
    }
    const float inv = 1.f / red[0];
#pragma unroll
    for (int i = 0; i < 16; i++)
        S[i * 256 + tid] = sv[i] * inv;
}

// ---------------------------------------------------------------------------
// weighted pool: Outv[b, h*64+d] += sum_{t chunk} w[t]*Src[b,t,h*64+d]
// grid (64,8) x 256; Outv pre-zeroed; atomicAdd partials.
// ---------------------------------------------------------------------------
__global__ __launch_bounds__(256) void k_pool(
    const float* __restrict__ ScT,
    const uint16_t* __restrict__ Src,
    float* __restrict__ Outv)
{
    const int bh = blockIdx.x, chunk = blockIdx.y;
    const int b = bh >> 3, h = bh & 7;
    const int t0 = chunk * 512;
    const float* wv = ScT + (size_t)bh * T_ + t0;
    __shared__ float part[4][64];
    const int tid = threadIdx.x;
    const int g = tid >> 6, d = tid & 63;

    float acc = 0.f;
    for (int t = g; t < 512; t += 4)
        acc += wv[t] * bf2f(Src[(size_t)(b * T_ + t0 + t) * E_ + h * D_ + d]);
    part[g][d] = acc;
    __syncthreads();
    if (tid < 64)
        atomicAdd(&Outv[b * E_ + h * D_ + tid],
                  part[0][tid] + part[1][tid] + part[2][tid] + part[3][tid]);
}

// ---------------------------------------------------------------------------
// WtOs[b][n][k] = WtO[n][k] * kpool[b][k] * qflat[b][k]   (bf16)
// ---------------------------------------------------------------------------
__global__ __launch_bounds__(256) void k_scale_wo(
    const uint16_t* __restrict__ WtO,
    const float* __restrict__ kpool, const float* __restrict__ qflat,
    uint16_t* __restrict__ WtOs)
{
    const int n = blockIdx.x, b = blockIdx.y;
    const float* s1 = kpool + b * E_;
    const float* s2 = qflat + b * E_;
    const int k = threadIdx.x * 2;
    ushort2 wv = *reinterpret_cast<const ushort2*>(&WtO[n * E_ + k]);
    ushort2 o;
    o.x = f2bf(bf2f(wv.x) * s1[k] * s2[k]);
    o.y = f2bf(bf2f(wv.y) * s1[k + 1] * s2[k + 1]);
    *reinterpret_cast<ushort2*>(&WtOs[((size_t)b * E_ + n) * E_ + k]) = o;
}

// ---------------------------------------------------------------------------
extern "C" void kernel_launch(void* const* d_in, const int* in_sizes, int n_in,
                              void* d_out, int out_size, void* d_ws, size_t ws_size,
                              hipStream_t stream)
{
    const float* q    = (const float*)d_in[0];
    const int*   mask = (const int*)d_in[3];
    const float* Wq   = (const float*)d_in[4];
    const float* bq   = (const float*)d_in[5];
    const float* Waq  = (const float*)d_in[6];
    const float* baq  = (const float*)d_in[7];
    const float* Wk   = (const float*)d_in[8];
    const float* bk   = (const float*)d_in[9];
    const float* Wak  = (const float*)d_in[10];
    const float* bak  = (const float*)d_in[11];
    const float* Wo   = (const float*)d_in[12];
    const float* bo   = (const float*)d_in[13];
    float* out = (float*)d_out;

    // ws layout capped at the round-4-proven ~74 MB footprint.
    char* ws = (char*)d_ws;
    uint16_t* query = (uint16_t*)(ws);                     // 33.55 MB
    uint16_t* key   = (uint16_t*)(ws + 33554432);          // 33.55 MB
    float*    scT   = (float*)(ws + 67108864);             // 1 MB
    float*    qflat = (float*)(ws + 68157440);             // 16 KB
    float*    kpool = (float*)(ws + 68173824);             // 16 KB
    uint16_t* WtQ   = (uint16_t*)(ws + 68190208);          // 512 KB
    uint16_t* WtK   = (uint16_t*)(ws + 68714496);          // 512 KB
    uint16_t* WtO   = (uint16_t*)(ws + 69238784);          // 512 KB
    uint16_t* WtOs  = (uint16_t*)(ws + 69763072);          // 4 MB (ends ~74 MB)
    // Xb staged inside d_out (67 MB f32): first 33.55 MB used as bf16 scratch.
    // d_out is dead until k_gemm2 fully overwrites it at the end of the graph.
    uint16_t* Xb    = (uint16_t*)d_out;

    hipMemsetAsync(qflat, 0, 32768, stream);               // qflat + kpool
    k_prep<<<8960, 256, 0, stream>>>(q, Wq, Wk, Wo, Xb, WtQ, WtK, WtO);
    k_gemm1<<<2048, 256, 0, stream>>>(Xb, WtQ, WtK, bq, bk, query, key);
    k_scores<<<512, 256, 0, stream>>>(query, nullptr, Waq, baq, scT);
    k_softmaxw<<<64, 256, 0, stream>>>(scT, mask);
    k_pool<<<dim3(64, 8), 256, 0, stream>>>(scT, query, qflat);
    k_scores<<<512, 256, 0, stream>>>(key, qflat, Wak, bak, scT);
    k_softmaxw<<<64, 256, 0, stream>>>(scT, mask);
    k_pool<<<dim3(64, 8), 256, 0, stream>>>(scT, key, kpool);
    k_scale_wo<<<dim3(512, 8), 256, 0, stream>>>(WtO, kpool, qflat, WtOs);
    k_gemm2<<<1024, 256, 0, stream>>>(query, WtOs, bo, out);
}